// Round 10
// baseline (251.585 us; speedup 1.0000x reference)
//
#include <hip/hip_runtime.h>
#include <cstddef>

// Shapes: B=8, CIN=128, N=2048, K=16, G=4, COUT=256, L=192, CL=48, NL=64, CNL=16
constexpr int NN = 2048;
constexpr int GG = 4;

// ---------------------------------------------------------------------------
// prep_q: Qbuf[g][c2][row] f32 (row<64: M_g[row][c2] = sum_o Wk[o][row]Wq[o][c2];
// row>=64: W2q_g[row-64][c2] = sum_o pe_w2[row-64][o]Wq[o][c2]), o in group g.
// ---------------------------------------------------------------------------
__global__ __launch_bounds__(256) void prep_q(const float* __restrict__ Wq,
                                              const float* __restrict__ Wk,
                                              const float* __restrict__ pe_w2,
                                              float* __restrict__ Qbuf) {
    const int g = blockIdx.x >> 6, c2 = blockIdx.x & 63;
    const int row = threadIdx.x;
    float acc = 0.f;
    if (row < 64) {
        for (int j = 0; j < 48; ++j) {
            const int o = g * 48 + j;
            acc = fmaf(Wk[o * 64 + row], Wq[o * 64 + c2], acc);
        }
    } else {
        const int d = row - 64;
        for (int j = 0; j < 48; ++j) {
            const int o = g * 48 + j;
            acc = fmaf(pe_w2[(size_t)d * 192 + o], Wq[o * 64 + c2], acc);
        }
    }
    Qbuf[((size_t)(g * 64 + c2) << 8) + row] = acc;
}

// ---------------------------------------------------------------------------
// local_v8: v7c structure + deep ILP (batched load issue) + P4 x-prefetch.
// launch_bounds(256,3) (proven spill-free). All logit math f32 (top-k safe).
// Block = (b, 8 n), 256 threads.
// ---------------------------------------------------------------------------
__global__ __launch_bounds__(256, 3) void local_v8(
    const float* __restrict__ x, const float* __restrict__ abs_x,
    const float* __restrict__ points, const float* __restrict__ Wv,
    const float* __restrict__ pe_w1, const float* __restrict__ pe_b1,
    const int* __restrict__ idx, const float* __restrict__ Qbuf,
    float* __restrict__ out, float* __restrict__ cent)
{
    const int bn = blockIdx.x;           // 2048 blocks
    const int b  = bn >> 8;
    const int n0 = (bn & 255) << 3;
    const int tid = threadIdx.x;

    __shared__ int   sidx[128];
    __shared__ float sa2[64][8];
    __shared__ __align__(16) float s_big[4224];       // sq / sw2 / sxw
    __shared__ float spart[128][9];
    __shared__ float s_small[544];                    // spts then satt

    float* sq   = s_big;     // sq[((g<<3)+nl)*65 + c2]
    float* sw2  = s_big;     // sw2[((g2<<3)+nl)*196 + d]
    float* sxw  = s_big;     // sxw[((g<<3)+nl)*132 + c]
    float* spts = s_small;   // spts[(c3*8+nl)*16 + kk]
    float* satt = s_small;   // satt[nl*68 + g*16 + kk]

    // ---- P0: idx + a2 ----
    if (tid < 128) sidx[tid] = idx[((size_t)b * NN + n0) * 16 + tid];
    for (int i = tid; i < 512; i += 256) {
        int c = i >> 3, nl = i & 7;
        sa2[c][nl] = abs_x[((size_t)b * 64 + c) * NN + n0 + nl];
    }
    __syncthreads();

    // ---- P1: points gather + q~ stage (thread = (g,row)), 8-batched loads ----
    for (int i = tid; i < 384; i += 256) {
        int c3 = i >> 7, r = i & 127;
        spts[(c3 * 8 + (r >> 4)) * 16 + (r & 15)] =
            points[((size_t)b * 3 + c3) * NN + sidx[r]];
    }
    {
        const int g = tid >> 6, row = tid & 63;
        const float* qb = Qbuf + (((size_t)g * 64) << 8) + row;
        float a0 = 0.f, a1 = 0.f, a2v = 0.f, a3 = 0.f,
              a4 = 0.f, a5 = 0.f, a6 = 0.f, a7 = 0.f;
        for (int c2 = 0; c2 < 64; c2 += 8) {
            float qv[8];
            #pragma unroll
            for (int j = 0; j < 8; ++j) qv[j] = qb[(c2 + j) << 8];
            #pragma unroll
            for (int j = 0; j < 8; ++j) {
                const float4 v0 = *(const float4*)&sa2[c2 + j][0];
                const float4 v1 = *(const float4*)&sa2[c2 + j][4];
                a0 = fmaf(qv[j], v0.x, a0); a1 = fmaf(qv[j], v0.y, a1);
                a2v = fmaf(qv[j], v0.z, a2v); a3 = fmaf(qv[j], v0.w, a3);
                a4 = fmaf(qv[j], v1.x, a4); a5 = fmaf(qv[j], v1.y, a5);
                a6 = fmaf(qv[j], v1.z, a6); a7 = fmaf(qv[j], v1.w, a7);
            }
        }
        const int base = (g << 3) * 65 + row;
        sq[base + 0 * 65] = a0; sq[base + 1 * 65] = a1;
        sq[base + 2 * 65] = a2v; sq[base + 3 * 65] = a3;
        sq[base + 4 * 65] = a4; sq[base + 5 * 65] = a5;
        sq[base + 6 * 65] = a6; sq[base + 7 * 65] = a7;
    }
    __syncthreads();

    // common thread mapping for P2a/P2b
    const int col = tid & 127, dh = tid >> 7;
    const int nlc = col >> 4, kkc = col & 15;

    // ---- P2a: logitA partials, 8-batched (16 loads in flight) ----
    {
        const float* xp = x + (((size_t)(b * 128 + dh * 32) * NN) + n0 + nlc) * 16 + kkc;
        const size_t cstr = (size_t)NN * 16;
        const float* q0 = &sq[((0 << 3) + nlc) * 65 + dh * 32];
        const float* q1 = &sq[((1 << 3) + nlc) * 65 + dh * 32];
        const float* q2 = &sq[((2 << 3) + nlc) * 65 + dh * 32];
        const float* q3 = &sq[((3 << 3) + nlc) * 65 + dh * 32];
        float a0 = 0.f, a1 = 0.f, a2v = 0.f, a3 = 0.f;
        for (int i0 = 0; i0 < 32; i0 += 8) {
            float lo[8], hi[8];
            #pragma unroll
            for (int j = 0; j < 8; ++j) {
                lo[j] = xp[(size_t)(i0 + j) * cstr];
                hi[j] = xp[(size_t)(i0 + j + 64) * cstr];
            }
            #pragma unroll
            for (int j = 0; j < 8; ++j) {
                const float xs = lo[j] + hi[j];
                a0 = fmaf(q0[i0 + j], xs, a0);
                a1 = fmaf(q1[i0 + j], xs, a1);
                a2v = fmaf(q2[i0 + j], xs, a2v);
                a3 = fmaf(q3[i0 + j], xs, a3);
            }
        }
        spart[col][dh * 4 + 0] = a0; spart[col][dh * 4 + 1] = a1;
        spart[col][dh * 4 + 2] = a2v; spart[col][dh * 4 + 3] = a3;
    }

    // ---- P4 x-prefetch: issue now, consumed after softmax (hides L3 latency) ----
    float4 xpre[16];
    #pragma unroll
    for (int t = 0; t < 4; ++t) {
        const int i2 = t * 256 + tid;
        const int c = i2 >> 3, nl = i2 & 7;
        const float* xp4 = x + (((size_t)(b * 128 + c) * NN) + n0 + nl) * 16;
        xpre[t * 4 + 0] = *(const float4*)(xp4);
        xpre[t * 4 + 1] = *(const float4*)(xp4 + 4);
        xpre[t * 4 + 2] = *(const float4*)(xp4 + 8);
        xpre[t * 4 + 3] = *(const float4*)(xp4 + 12);
    }
    __syncthreads();   // sq dead; s_big free for sw2

    // ---- P2b: logitB in two 2-group passes, staging 8-batched ----
    const float r0 = spts[(0 * 8 + nlc) * 16 + kkc] - spts[(0 * 8 + nlc) * 16];
    const float r1 = spts[(1 * 8 + nlc) * 16 + kkc] - spts[(1 * 8 + nlc) * 16];
    const float r2 = spts[(2 * 8 + nlc) * 16 + kkc] - spts[(2 * 8 + nlc) * 16];
    #pragma unroll
    for (int p = 0; p < 2; ++p) {
        if (tid < 192) {            // stage w~[2p..2p+1][tid(d)][8 nl]
            const int d = tid;
            float w00=0.f,w01=0.f,w02=0.f,w03=0.f,w04=0.f,w05=0.f,w06=0.f,w07=0.f;
            float w10=0.f,w11=0.f,w12=0.f,w13=0.f,w14=0.f,w15=0.f,w16=0.f,w17=0.f;
            const float* qb0 = Qbuf + (((size_t)(2 * p + 0) * 64) << 8) + 64 + d;
            const float* qb1 = Qbuf + (((size_t)(2 * p + 1) * 64) << 8) + 64 + d;
            for (int c2 = 0; c2 < 64; c2 += 4) {
                float qv0[4], qv1[4];
                #pragma unroll
                for (int j = 0; j < 4; ++j) {
                    qv0[j] = qb0[(c2 + j) << 8];
                    qv1[j] = qb1[(c2 + j) << 8];
                }
                #pragma unroll
                for (int j = 0; j < 4; ++j) {
                    const float4 v0 = *(const float4*)&sa2[c2 + j][0];
                    const float4 v1 = *(const float4*)&sa2[c2 + j][4];
                    w00 = fmaf(qv0[j], v0.x, w00); w01 = fmaf(qv0[j], v0.y, w01);
                    w02 = fmaf(qv0[j], v0.z, w02); w03 = fmaf(qv0[j], v0.w, w03);
                    w04 = fmaf(qv0[j], v1.x, w04); w05 = fmaf(qv0[j], v1.y, w05);
                    w06 = fmaf(qv0[j], v1.z, w06); w07 = fmaf(qv0[j], v1.w, w07);
                    w10 = fmaf(qv1[j], v0.x, w10); w11 = fmaf(qv1[j], v0.y, w11);
                    w12 = fmaf(qv1[j], v0.z, w12); w13 = fmaf(qv1[j], v0.w, w13);
                    w14 = fmaf(qv1[j], v1.x, w14); w15 = fmaf(qv1[j], v1.y, w15);
                    w16 = fmaf(qv1[j], v1.z, w16); w17 = fmaf(qv1[j], v1.w, w17);
                }
            }
            sw2[(0 * 8 + 0) * 196 + d] = w00; sw2[(0 * 8 + 1) * 196 + d] = w01;
            sw2[(0 * 8 + 2) * 196 + d] = w02; sw2[(0 * 8 + 3) * 196 + d] = w03;
            sw2[(0 * 8 + 4) * 196 + d] = w04; sw2[(0 * 8 + 5) * 196 + d] = w05;
            sw2[(0 * 8 + 6) * 196 + d] = w06; sw2[(0 * 8 + 7) * 196 + d] = w07;
            sw2[(1 * 8 + 0) * 196 + d] = w10; sw2[(1 * 8 + 1) * 196 + d] = w11;
            sw2[(1 * 8 + 2) * 196 + d] = w12; sw2[(1 * 8 + 3) * 196 + d] = w13;
            sw2[(1 * 8 + 4) * 196 + d] = w14; sw2[(1 * 8 + 5) * 196 + d] = w15;
            sw2[(1 * 8 + 6) * 196 + d] = w16; sw2[(1 * 8 + 7) * 196 + d] = w17;
        }
        __syncthreads();
        {
            float pB0 = 0.f, pB1 = 0.f;
            const float* w0 = &sw2[(0 * 8 + nlc) * 196];
            const float* w1 = &sw2[(1 * 8 + nlc) * 196];
            const int d0 = dh * 96;
            #pragma unroll 2
            for (int d = d0; d < d0 + 96; d += 4) {
                const float4 w1a = *(const float4*)&pe_w1[d];
                const float4 w1b = *(const float4*)&pe_w1[192 + d];
                const float4 w1c = *(const float4*)&pe_w1[384 + d];
                const float4 bb  = *(const float4*)&pe_b1[d];
                const float h0 = fmaxf(fmaf(r0, w1a.x, fmaf(r1, w1b.x, fmaf(r2, w1c.x, bb.x))), 0.f);
                const float h1 = fmaxf(fmaf(r0, w1a.y, fmaf(r1, w1b.y, fmaf(r2, w1c.y, bb.y))), 0.f);
                const float h2 = fmaxf(fmaf(r0, w1a.z, fmaf(r1, w1b.z, fmaf(r2, w1c.z, bb.z))), 0.f);
                const float h3 = fmaxf(fmaf(r0, w1a.w, fmaf(r1, w1b.w, fmaf(r2, w1c.w, bb.w))), 0.f);
                const float4 wa = *(const float4*)&w0[d];
                const float4 wb = *(const float4*)&w1[d];
                pB0 = fmaf(h0, wa.x, fmaf(h1, wa.y, fmaf(h2, wa.z, fmaf(h3, wa.w, pB0))));
                pB1 = fmaf(h0, wb.x, fmaf(h1, wb.y, fmaf(h2, wb.z, fmaf(h3, wb.w, pB1))));
            }
            spart[col][dh * 4 + 2 * p + 0] += pB0;
            spart[col][dh * 4 + 2 * p + 1] += pB1;
        }
        __syncthreads();
    }

    // ---- P3: softmax over kk per (g,nl) ----
    if (tid < 32) {
        const int g = tid >> 3, nl = tid & 7;
        float lg[16], m = -1e30f;
        #pragma unroll
        for (int kk = 0; kk < 16; ++kk) {
            const int cc = nl * 16 + kk;
            lg[kk] = spart[cc][g] + spart[cc][4 + g];
            m = fmaxf(m, lg[kk]);
        }
        float s = 0.f;
        #pragma unroll
        for (int kk = 0; kk < 16; ++kk) { lg[kk] = __expf(lg[kk] - m); s += lg[kk]; }
        const float inv = 1.f / s;
        #pragma unroll
        for (int kk = 0; kk < 16; ++kk) satt[nl * 68 + g * 16 + kk] = lg[kk] * inv;
    }
    __syncthreads();

    // ---- P4: xw[g][nl][c] from prefetched x ----
    #pragma unroll
    for (int t = 0; t < 4; ++t) {
        const int i2 = t * 256 + tid;
        const int c = i2 >> 3, nl = i2 & 7;
        const float4 x0 = xpre[t * 4 + 0];
        const float4 x1 = xpre[t * 4 + 1];
        const float4 x2 = xpre[t * 4 + 2];
        const float4 x3 = xpre[t * 4 + 3];
        const float* at = &satt[nl * 68];
        #pragma unroll
        for (int g = 0; g < 4; ++g) {
            const float* a = at + g * 16;
            float v = 0.f;
            v = fmaf(x0.x, a[0],  v); v = fmaf(x0.y, a[1],  v);
            v = fmaf(x0.z, a[2],  v); v = fmaf(x0.w, a[3],  v);
            v = fmaf(x1.x, a[4],  v); v = fmaf(x1.y, a[5],  v);
            v = fmaf(x1.z, a[6],  v); v = fmaf(x1.w, a[7],  v);
            v = fmaf(x2.x, a[8],  v); v = fmaf(x2.y, a[9],  v);
            v = fmaf(x2.z, a[10], v); v = fmaf(x2.w, a[11], v);
            v = fmaf(x3.x, a[12], v); v = fmaf(x3.y, a[13], v);
            v = fmaf(x3.z, a[14], v); v = fmaf(x3.w, a[15], v);
            sxw[((g << 3) + nl) * 132 + c] = v;
        }
    }
    __syncthreads();

    // ---- P5: out[o][n] = Wv[o,:] . xw[g(o)][nl][:] ----
    #pragma unroll
    for (int rep = 0; rep < 6; ++rep) {
        const int i = rep * 256 + tid;
        const int o = i >> 3, nl = i & 7;
        const int g = o / 48;
        const float* wv  = Wv + (size_t)o * 128;
        const float* xwp = &sxw[((g << 3) + nl) * 132];
        float a = 0.f;
        #pragma unroll 8
        for (int c = 0; c < 128; c += 4) {
            const float4 w4  = *(const float4*)(wv + c);
            const float4 xw4 = *(const float4*)(xwp + c);
            a = fmaf(w4.x, xw4.x, fmaf(w4.y, xw4.y, fmaf(w4.z, xw4.z, fmaf(w4.w, xw4.w, a))));
        }
        out[(((size_t)b << 8) + o) * NN + n0 + nl] = a;
    }

    // ---- P6: deferred cent atomic scatter ----
    if (tid < 32) {
        const int g = tid >> 3, nl = tid & 7;
        #pragma unroll
        for (int kk = 0; kk < 16; ++kk)
            atomicAdd(&cent[((size_t)(b * GG + g) << 11) + sidx[nl * 16 + kk]],
                      satt[nl * 68 + g * 16 + kk]);
    }
}

// ---------------------------------------------------------------------------
// Kernel C: per (b,g): chunked wave top-16 (exact, lowest-idx tie-break),
// then nonlocal prep. 512 threads.
// ---------------------------------------------------------------------------
__global__ __launch_bounds__(512) void topk_prep_kernel(
    const float* __restrict__ abs_x, const float* __restrict__ points,
    const float* __restrict__ Wnk, const float* __restrict__ Wnv2,
    const float* __restrict__ npe_w1, const float* __restrict__ npe_b1,
    const float* __restrict__ npe_w2, const float* __restrict__ npe_b2,
    const float* __restrict__ cent,
    float* __restrict__ nkpe, float* __restrict__ nv2j, float* __restrict__ tanhv)
{
    const int bg  = blockIdx.x;
    const int b   = bg >> 2, g = bg & 3;
    const int tid = threadIdx.x;
    const int wave = tid >> 6, lane = tid & 63;
    __shared__ float sc[2048];
    __shared__ float cval[128]; __shared__ int cidx[128];
    __shared__ float svals[16]; __shared__ int sinds[16];
    __shared__ float srel[3][16];
    __shared__ float sh2[16][16];

    for (int i = tid; i < 2048; i += 512) sc[i] = cent[((size_t)bg << 11) + i];
    __syncthreads();

    // phase 1: each wave extracts top-16 of its 256-element chunk (no barriers)
    {
        float v[4]; int ix[4];
        #pragma unroll
        for (int j = 0; j < 4; ++j) {
            const int i = wave * 256 + j * 64 + lane;
            v[j] = sc[i]; ix[j] = i;
        }
        for (int t = 0; t < 16; ++t) {
            float bv = v[0]; int bi = ix[0];
            #pragma unroll
            for (int j = 1; j < 4; ++j)
                if (v[j] > bv || (v[j] == bv && ix[j] < bi)) { bv = v[j]; bi = ix[j]; }
            float wv_ = bv; int wi_ = bi;
            #pragma unroll
            for (int off = 1; off < 64; off <<= 1) {
                const float ov = __shfl_xor(wv_, off, 64);
                const int   oi = __shfl_xor(wi_, off, 64);
                if (ov > wv_ || (ov == wv_ && oi < wi_)) { wv_ = ov; wi_ = oi; }
            }
            #pragma unroll
            for (int j = 0; j < 4; ++j)
                if (ix[j] == wi_) { v[j] = -1e30f; ix[j] = 1 << 30; }
            if (lane == 0) { cval[wave * 16 + t] = wv_; cidx[wave * 16 + t] = wi_; }
        }
    }
    __syncthreads();

    // phase 2: wave 0 merges the 128 candidates -> global top-16
    if (wave == 0) {
        float m0 = cval[lane], m1 = cval[64 + lane];
        int   j0 = cidx[lane], j1 = cidx[64 + lane];
        for (int t = 0; t < 16; ++t) {
            float bv; int bi;
            if (m0 > m1 || (m0 == m1 && j0 < j1)) { bv = m0; bi = j0; }
            else { bv = m1; bi = j1; }
            float wv_ = bv; int wi_ = bi;
            #pragma unroll
            for (int off = 1; off < 64; off <<= 1) {
                const float ov = __shfl_xor(wv_, off, 64);
                const int   oi = __shfl_xor(wi_, off, 64);
                if (ov > wv_ || (ov == wv_ && oi < wi_)) { wv_ = ov; wi_ = oi; }
            }
            if (j0 == wi_) { m0 = -1e30f; j0 = 1 << 30; }
            if (j1 == wi_) { m1 = -1e30f; j1 = 1 << 30; }
            if (lane == 0) { svals[t] = wv_; sinds[t] = wi_; }
        }
    }
    __syncthreads();

    if (tid < 48) {
        int c = tid >> 4, j = tid & 15;
        srel[c][j] = points[((size_t)b * 3 + c) * NN + sinds[j]]
                   - points[((size_t)b * 3 + c) * NN + sinds[0]];
    }
    __syncthreads();
    if (tid < 256) {
        int j = tid >> 4, d = tid & 15;
        float a = npe_b1[g * 16 + d];
        #pragma unroll
        for (int c = 0; c < 3; ++c) a = fmaf(srel[c][j], npe_w1[((g * 3 + c) << 4) + d], a);
        sh2[j][d] = fmaxf(a, 0.f);
    }
    __syncthreads();
    if (tid < 256) {
        int c = tid >> 4, j = tid & 15;
        float a = npe_b2[g * 16 + c];
        #pragma unroll
        for (int d = 0; d < 16; ++d) a = fmaf(sh2[j][d], npe_w2[((g * 16 + d) << 4) + c], a);
        float nk = 0.f, nv = 0.f;
        const int colj = sinds[j];
        const float* a2  = abs_x + (size_t)b * 64 * NN + colj;
        const float* wkr = Wnk  + ((size_t)(g * 16 + c) << 6);
        const float* wvr = Wnv2 + ((size_t)(g * 16 + c) << 6);
        for (int ci = 0; ci < 64; ++ci) {
            float av = a2[(size_t)ci * NN];
            nk = fmaf(wkr[ci], av, nk);
            nv = fmaf(wvr[ci], av, nv);
        }
        nkpe[((size_t)bg << 8) + (c << 4) + j] = nk + a;
        nv2j[((size_t)bg << 8) + (c << 4) + j] = nv;
    }
    if (tid < 16) tanhv[(bg << 4) + tid] = tanhf(svals[tid]);
}

// ---------------------------------------------------------------------------
// Kernel D: nonlocal branch (unchanged).
// ---------------------------------------------------------------------------
__global__ __launch_bounds__(256) void nonlocal_kernel(
    const float* __restrict__ abs_x,
    const float* __restrict__ Wnq, const float* __restrict__ Wnv1, const float* __restrict__ Wnv2,
    const float* __restrict__ nkpe, const float* __restrict__ nv2j, const float* __restrict__ tanhv,
    float* __restrict__ out)
{
    const int blk = blockIdx.x;
    const int b   = blk >> 5;
    const int n0  = (blk & 31) << 6;
    const int tid = threadIdx.x;
    const int nl  = tid & 63;
    const int g   = tid >> 6;

    __shared__ float sa2[64][64];
    __shared__ float snkpe[4][16][16];
    __shared__ float snv2j[4][16][16];
    __shared__ float stanh[4][16];

    for (int i = tid; i < 64 * 64; i += 256) {
        int ci = i >> 6, c2 = i & 63;
        sa2[ci][c2] = abs_x[((size_t)b * 64 + ci) * NN + n0 + c2];
    }
    for (int i = tid; i < 1024; i += 256) {
        ((float*)snkpe)[i] = nkpe[((size_t)b << 10) + i];
        ((float*)snv2j)[i] = nv2j[((size_t)b << 10) + i];
    }
    if (tid < 64) ((float*)stanh)[tid] = tanhv[(b << 6) + tid];
    __syncthreads();

    float nq[16], nv1[16], nv2[16];
    #pragma unroll
    for (int c = 0; c < 16; ++c) { nq[c] = 0.f; nv1[c] = 0.f; nv2[c] = 0.f; }
    const float* wq  = Wnq  + (size_t)(g << 4) * 64;
    const float* wv1 = Wnv1 + (size_t)(g << 4) * 64;
    const float* wv2 = Wnv2 + (size_t)(g << 4) * 64;
    for (int ci = 0; ci < 64; ++ci) {
        const float a = sa2[ci][nl];
        #pragma unroll
        for (int c = 0; c < 16; ++c) {
            nq[c]  = fmaf(wq [(c << 6) + ci], a, nq[c]);
            nv1[c] = fmaf(wv1[(c << 6) + ci], a, nv1[c]);
            nv2[c] = fmaf(wv2[(c << 6) + ci], a, nv2[c]);
        }
    }

    float lg[16];
    #pragma unroll
    for (int j = 0; j < 16; ++j) {
        float a = 0.f;
        #pragma unroll
        for (int c = 0; c < 16; ++c) a = fmaf(nq[c], snkpe[g][c][j], a);
        lg[j] = a;
    }
    float m = lg[0];
    #pragma unroll
    for (int j = 1; j < 16; ++j) m = fmaxf(m, lg[j]);
    float s = 0.f;
    float w[16];
    #pragma unroll
    for (int j = 0; j < 16; ++j) { w[j] = __expf(lg[j] - m); s += w[j]; }
    const float inv = 1.f / s;
    float ws = 0.f;
    #pragma unroll
    for (int j = 0; j < 16; ++j) { w[j] = w[j] * inv * stanh[g][j]; ws += w[j]; }
    #pragma unroll
    for (int c = 0; c < 16; ++c) {
        float v = (nv1[c] - nv2[c]) * ws;
        #pragma unroll
        for (int j = 0; j < 16; ++j) v = fmaf(w[j], snv2j[g][c][j], v);
        out[(((size_t)b << 8) + 192 + (g << 4) + c) * NN + n0 + nl] = v;
    }
}

// ---------------------------------------------------------------------------
extern "C" void kernel_launch(void* const* d_in, const int* in_sizes, int n_in,
                              void* d_out, int out_size, void* d_ws, size_t ws_size,
                              hipStream_t stream)
{
    (void)in_sizes; (void)n_in; (void)out_size; (void)ws_size;
    const float* x      = (const float*)d_in[0];
    const float* abs_x  = (const float*)d_in[1];
    const float* points = (const float*)d_in[2];
    const float* Wq     = (const float*)d_in[3];
    const float* Wk     = (const float*)d_in[4];
    const float* Wv     = (const float*)d_in[5];
    const float* Wnq    = (const float*)d_in[6];
    const float* Wnk    = (const float*)d_in[7];
    const float* Wnv1   = (const float*)d_in[8];
    const float* Wnv2   = (const float*)d_in[9];
    const float* pe_w1  = (const float*)d_in[10];
    const float* pe_b1  = (const float*)d_in[11];
    const float* pe_w2  = (const float*)d_in[12];
    // pe_b2 (d_in[13]): constant logit shift per (g,n) -> cancels in softmax
    const float* npe_w1 = (const float*)d_in[14];
    const float* npe_b1 = (const float*)d_in[15];
    const float* npe_w2 = (const float*)d_in[16];
    const float* npe_b2 = (const float*)d_in[17];
    const int*   idx    = (const int*)d_in[18];
    float* out = (float*)d_out;

    // ws layout (floats): cent[65536] | Qbuf[65536] | nkpe[8192] | nv2j[8192] | tanh[512]
    float* cent  = (float*)d_ws;
    float* Qbuf  = cent + 65536;
    float* nkpeW = Qbuf + 65536;
    float* nv2jW = nkpeW + 8192;
    float* tanhW = nv2jW + 8192;

    hipMemsetAsync(cent, 0, (size_t)65536 * sizeof(float), stream);
    prep_q<<<256, 256, 0, stream>>>(Wq, Wk, pe_w2, Qbuf);
    local_v8<<<2048, 256, 0, stream>>>(x, abs_x, points, Wv, pe_w1, pe_b1,
                                       idx, Qbuf, out, cent);
    topk_prep_kernel<<<32, 512, 0, stream>>>(abs_x, points, Wnk, Wnv2,
                                             npe_w1, npe_b1, npe_w2, npe_b2,
                                             cent, nkpeW, nv2jW, tanhW);
    nonlocal_kernel<<<8 * 32, 256, 0, stream>>>(abs_x, Wnq, Wnv1, Wnv2,
                                                nkpeW, nv2jW, tanhW, out);
}